// Round 3
// baseline (678.551 us; speedup 1.0000x reference)
//
#include <hip/hip_runtime.h>
#include <math.h>

#define B_  64
#define Cc  128
#define L_  3136

typedef __bf16 b8v __attribute__((ext_vector_type(8)));
typedef __bf16 b4v __attribute__((ext_vector_type(4)));
typedef float  f4v __attribute__((ext_vector_type(4)));

__device__ __forceinline__ f4v mfma16(b8v a, b8v b, f4v c) {
    return __builtin_amdgcn_mfma_f32_16x16x32_bf16(a, b, c, 0, 0, 0);
}
__device__ __forceinline__ int region(int h, int w) {
    int a = (h < 49) ? 0 : ((h < 53) ? 1 : 2);
    int b = (w < 49) ? 0 : ((w < 53) ? 1 : 2);
    return a * 3 + b;
}

// ws layout: bf16 weights [0,196608) elems; biasmask f32[4][4][64][64] at byte 393216
__global__ __launch_bounds__(256) void prep_kernel(
    const float* __restrict__ qkv_w, const float* __restrict__ proj_w,
    const float* __restrict__ fc1_w, const float* __restrict__ fc2_w,
    const float* __restrict__ rpb,
    __bf16* __restrict__ wsb, float* __restrict__ bm)
{
    int i = blockIdx.x * 256 + threadIdx.x;
    if      (i <  49152) wsb[i] = (__bf16)qkv_w[i];
    else if (i <  65536) wsb[i] = (__bf16)proj_w[i - 49152];
    else if (i < 131072) wsb[i] = (__bf16)fc1_w[i - 65536];
    else if (i < 196608) wsb[i] = (__bf16)fc2_w[i - 131072];
    else {
        int idx = i - 196608;  // ((wt*4+h)*64+ii)*64+jj
        int jj = idx & 63, ii = (idx >> 6) & 63, h = (idx >> 12) & 3, wt = idx >> 14;
        float v;
        if (jj >= 49)      v = -1e30f;
        else if (ii >= 49) v = 0.f;
        else {
            int ih = ii / 7, iw = ii - ih * 7, jh = jj / 7, jw = jj - jh * 7;
            v = rpb[((ih - jh + 6) * 13 + (iw - jw + 6)) * 4 + h];
            int WH = (wt & 2) ? 49 : 0, WW = (wt & 1) ? 49 : 0;
            if (region(WH + ih, WW + iw) != region(WH + jh, WW + jw)) v -= 100.f;
        }
        bm[idx] = v;
    }
}

// ---- kernel A v3: LN1 + SW-MSA + proj + residual, ONE barrier per block ----
// Per-wave scratch for all D->A transposes (wave-local, in-order DS, no sync);
// only K rows and V^T are shared. LDS 53248 -> 3 blocks/CU.
__global__ __launch_bounds__(256, 3) void swin_kernel(
    const float* __restrict__ x,
    const float* __restrict__ g1, const float* __restrict__ b1,
    const float* __restrict__ qkv_b, const float* __restrict__ proj_b,
    const __bf16* __restrict__ wqkv, const __bf16* __restrict__ wproj,
    const float* __restrict__ bm,
    float* __restrict__ out)
{
    __shared__ __bf16 K_s[64 * 136];        // K rows (all heads), +8 pad
    __shared__ __bf16 VT_s[128 * 72];       // V^T [d][token+8 pad]
    __shared__ __bf16 scr_s[4][16 * 136];   // per-wave scratch

    const int tid = threadIdx.x, w = tid >> 6, lane = tid & 63;
    const int quad = lane >> 4, r16 = lane & 15;
    const int blk = blockIdx.x, b = blk >> 6, wi = blk & 63;
    const int wh = wi >> 3, ww = wi & 7;
    const int wt = ((wh == 7) ? 2 : 0) | ((ww == 7) ? 1 : 0);
    const float scale = 0.17677669529663687f;  // 1/sqrt(32)
    __bf16* scr = scr_s[w];

    // ---- LN1 (wave-local): each 16-lane quad-group handles one row ----
    {
        f4v gg0 = *(const f4v*)(g1 + r16 * 8), gg1 = *(const f4v*)(g1 + r16 * 8 + 4);
        f4v bb0 = *(const f4v*)(b1 + r16 * 8), bb1 = *(const f4v*)(b1 + r16 * 8 + 4);
        #pragma unroll
        for (int it = 0; it < 4; it++) {
            int local = it * 4 + quad;
            int t = w * 16 + local;
            b8v o;
            #pragma unroll
            for (int e = 0; e < 8; e++) o[e] = (__bf16)0.f;
            if (t < 49) {   // group-uniform branch (t depends on w,it,quad only)
                int th = t / 7, tw = t - th * 7;
                int sh = wh * 7 + th + 3; if (sh >= 56) sh -= 56;
                int sw = ww * 7 + tw + 3; if (sw >= 56) sw -= 56;
                const float* xp = x + (b * L_ + sh * 56 + sw) * Cc + r16 * 8;
                f4v x0 = *(const f4v*)(xp), x1 = *(const f4v*)(xp + 4);
                float s = 0.f, q = 0.f;
                #pragma unroll
                for (int e = 0; e < 4; e++) {
                    s += x0[e] + x1[e];
                    q += x0[e] * x0[e] + x1[e] * x1[e];
                }
                s += __shfl_xor(s, 1, 64); q += __shfl_xor(q, 1, 64);
                s += __shfl_xor(s, 2, 64); q += __shfl_xor(q, 2, 64);
                s += __shfl_xor(s, 4, 64); q += __shfl_xor(q, 4, 64);
                s += __shfl_xor(s, 8, 64); q += __shfl_xor(q, 8, 64);
                float mu = s * (1.f / 128.f);
                float rs = rsqrtf(q * (1.f / 128.f) - mu * mu + 1e-5f);
                #pragma unroll
                for (int e = 0; e < 4; e++) {
                    o[e]     = (__bf16)((x0[e] - mu) * rs * gg0[e] + bb0[e]);
                    o[4 + e] = (__bf16)((x1[e] - mu) * rs * gg1[e] + bb1[e]);
                }
            }
            *(b8v*)(scr + local * 136 + r16 * 8) = o;
        }
    }

    // LN1 A-frags -> regs (cross-lane read of wave-local scratch; DS in-order)
    b8v A0 = *(const b8v*)(scr + r16 * 136);
    b8v A1 = *(const b8v*)(scr + r16 * 136 + 32);
    b8v A2 = *(const b8v*)(scr + r16 * 136 + 64);
    b8v A3 = *(const b8v*)(scr + r16 * 136 + 96);

    // ---- Q (all heads): D-frags -> scr (overwrites LN1 data after A reads) ----
    #pragma unroll
    for (int nt = 0; nt < 8; nt++) {
        const __bf16* bp = wqkv + (nt * 16 + r16) * 128 + quad * 8;
        f4v acc = {0.f, 0.f, 0.f, 0.f};
        acc = mfma16(A0, *(const b8v*)(bp),      acc);
        acc = mfma16(A1, *(const b8v*)(bp + 32), acc);
        acc = mfma16(A2, *(const b8v*)(bp + 64), acc);
        acc = mfma16(A3, *(const b8v*)(bp + 96), acc);
        float bias = qkv_b[nt * 16 + r16];
        #pragma unroll
        for (int r = 0; r < 4; r++)
            scr[(quad * 4 + r) * 136 + nt * 16 + r16] = (__bf16)((acc[r] + bias) * scale);
    }
    // Q A-frags per head -> regs
    b8v qf[4];
    #pragma unroll
    for (int h = 0; h < 4; h++)
        qf[h] = *(const b8v*)(scr + r16 * 136 + h * 32 + quad * 8);

    // ---- K (all heads) -> shared K_s rows of this wave's strip ----
    #pragma unroll
    for (int nt = 0; nt < 8; nt++) {
        const __bf16* bp = wqkv + (128 + nt * 16 + r16) * 128 + quad * 8;
        f4v acc = {0.f, 0.f, 0.f, 0.f};
        acc = mfma16(A0, *(const b8v*)(bp),      acc);
        acc = mfma16(A1, *(const b8v*)(bp + 32), acc);
        acc = mfma16(A2, *(const b8v*)(bp + 64), acc);
        acc = mfma16(A3, *(const b8v*)(bp + 96), acc);
        float bias = qkv_b[128 + nt * 16 + r16];
        #pragma unroll
        for (int r = 0; r < 4; r++)
            K_s[(w * 16 + quad * 4 + r) * 136 + nt * 16 + r16] = (__bf16)(acc[r] + bias);
    }
    // ---- V (all heads) -> shared VT_s, packed 4-wide stores ----
    #pragma unroll
    for (int nt = 0; nt < 8; nt++) {
        const __bf16* bp = wqkv + (256 + nt * 16 + r16) * 128 + quad * 8;
        f4v acc = {0.f, 0.f, 0.f, 0.f};
        acc = mfma16(A0, *(const b8v*)(bp),      acc);
        acc = mfma16(A1, *(const b8v*)(bp + 32), acc);
        acc = mfma16(A2, *(const b8v*)(bp + 64), acc);
        acc = mfma16(A3, *(const b8v*)(bp + 96), acc);
        float bias = qkv_b[256 + nt * 16 + r16];
        b4v pk;
        #pragma unroll
        for (int r = 0; r < 4; r++) pk[r] = (__bf16)(acc[r] + bias);
        *(b4v*)(VT_s + (nt * 16 + r16) * 72 + w * 16 + quad * 4) = pk;
    }
    __syncthreads();   // the ONLY barrier

    // ---- all 4 heads: S -> softmax -> PV, barrier-free ----
    f4v o_acc[4][2];
    #pragma unroll
    for (int h = 0; h < 4; h++)
        #pragma unroll
        for (int n = 0; n < 2; n++)
            o_acc[h][n] = (f4v){0.f, 0.f, 0.f, 0.f};

    const float* bmw = bm + wt * 4 * 4096;

    #pragma unroll
    for (int h = 0; h < 4; h++) {
        f4v s[4];
        #pragma unroll
        for (int nt = 0; nt < 4; nt++) {
            b8v kf = *(const b8v*)(K_s + (nt * 16 + r16) * 136 + h * 32 + quad * 8);
            f4v z = {0.f, 0.f, 0.f, 0.f};
            s[nt] = mfma16(qf[h], kf, z);
        }
        const float* bmp = bmw + h * 4096 + (w * 16 + quad * 4) * 64 + r16;
        #pragma unroll
        for (int nt = 0; nt < 4; nt++)
            #pragma unroll
            for (int r = 0; r < 4; r++)
                s[nt][r] += bmp[r * 64 + nt * 16];
        // softmax
        {
            float mx[4], sm[4];
            #pragma unroll
            for (int r = 0; r < 4; r++)
                mx[r] = fmaxf(fmaxf(s[0][r], s[1][r]), fmaxf(s[2][r], s[3][r]));
            #pragma unroll
            for (int mk = 1; mk < 16; mk <<= 1)
                #pragma unroll
                for (int r = 0; r < 4; r++)
                    mx[r] = fmaxf(mx[r], __shfl_xor(mx[r], mk, 64));
            #pragma unroll
            for (int r = 0; r < 4; r++) {
                s[0][r] = expf(s[0][r] - mx[r]);
                s[1][r] = expf(s[1][r] - mx[r]);
                s[2][r] = expf(s[2][r] - mx[r]);
                s[3][r] = expf(s[3][r] - mx[r]);
                sm[r] = s[0][r] + s[1][r] + s[2][r] + s[3][r];
            }
            #pragma unroll
            for (int mk = 1; mk < 16; mk <<= 1)
                #pragma unroll
                for (int r = 0; r < 4; r++)
                    sm[r] += __shfl_xor(sm[r], mk, 64);
            #pragma unroll
            for (int r = 0; r < 4; r++) {
                float inv = 1.f / sm[r];
                s[0][r] *= inv; s[1][r] *= inv; s[2][r] *= inv; s[3][r] *= inv;
            }
        }
        // P bounce through wave-local scratch (D->A)
        #pragma unroll
        for (int nt = 0; nt < 4; nt++)
            #pragma unroll
            for (int r = 0; r < 4; r++)
                scr[(quad * 4 + r) * 136 + nt * 16 + r16] = (__bf16)s[nt][r];
        #pragma unroll
        for (int ks = 0; ks < 2; ks++) {
            b8v pf = *(const b8v*)(scr + r16 * 136 + ks * 32 + quad * 8);
            #pragma unroll
            for (int nt = 0; nt < 2; nt++) {
                b8v vf = *(const b8v*)(VT_s + (h * 32 + nt * 16 + r16) * 72 + ks * 32 + quad * 8);
                o_acc[h][nt] = mfma16(pf, vf, o_acc[h][nt]);
            }
        }
    }

    // ---- O bounce (wave-local) + proj + residual ----
    #pragma unroll
    for (int h = 0; h < 4; h++)
        #pragma unroll
        for (int nt = 0; nt < 2; nt++)
            #pragma unroll
            for (int r = 0; r < 4; r++)
                scr[(quad * 4 + r) * 136 + h * 32 + nt * 16 + r16] = (__bf16)o_acc[h][nt][r];
    {
        b8v O0 = *(const b8v*)(scr + r16 * 136);
        b8v O1 = *(const b8v*)(scr + r16 * 136 + 32);
        b8v O2 = *(const b8v*)(scr + r16 * 136 + 64);
        b8v O3 = *(const b8v*)(scr + r16 * 136 + 96);
        #pragma unroll
        for (int nt = 0; nt < 8; nt++) {
            const __bf16* bp = wproj + (nt * 16 + r16) * 128 + quad * 8;
            f4v acc = {0.f, 0.f, 0.f, 0.f};
            acc = mfma16(O0, *(const b8v*)(bp),      acc);
            acc = mfma16(O1, *(const b8v*)(bp + 32), acc);
            acc = mfma16(O2, *(const b8v*)(bp + 64), acc);
            acc = mfma16(O3, *(const b8v*)(bp + 96), acc);
            int col = nt * 16 + r16;
            float pb = proj_b[col];
            #pragma unroll
            for (int r = 0; r < 4; r++) {
                int t = w * 16 + quad * 4 + r;
                if (t < 49) {
                    int th = t / 7, tw = t - th * 7;
                    int sh = wh * 7 + th + 3; if (sh >= 56) sh -= 56;
                    int sw = ww * 7 + tw + 3; if (sw >= 56) sw -= 56;
                    int off = (b * L_ + sh * 56 + sw) * Cc + col;
                    out[off] = x[off] + acc[r] + pb;
                }
            }
        }
    }
}

// ---- kernel B v2: LN2 + fc1 + GELU + fc2 + residual ----
// block = 32 contiguous tokens, 4 waves. Weights column-sliced per wave:
// each weight element loaded ONCE per block. LDS union 33280 B -> 4 blocks/CU.
__global__ __launch_bounds__(256, 4) void mlp_kernel(
    float* __restrict__ out,
    const float* __restrict__ g2, const float* __restrict__ b2,
    const __bf16* __restrict__ wfc1, const __bf16* __restrict__ wfc2,
    const float* __restrict__ fc1_b, const float* __restrict__ fc2_b)
{
    __shared__ __align__(16) char u_s[33280];
    __bf16* x2  = (__bf16*)u_s;     // [32][136] LN2 output
    __bf16* h1  = (__bf16*)u_s;     // [32][520] GELU(fc1) output
    float*  o_s = (float*)u_s;      // [32][130] fc2 output (pre-residual)

    const int tid = threadIdx.x, w = tid >> 6, lane = tid & 63;
    const int quad = lane >> 4, r16 = lane & 15;
    const int rowbase = blockIdx.x * 32;

    // ---- LN2: wave w -> rows w*8..w*8+7; lane: r=lane>>3, cols (lane&7)*16..+15 ----
    {
        const int r = lane >> 3, sub = lane & 7;
        const float* xp = out + (rowbase + w * 8 + r) * Cc + sub * 16;
        f4v xa[4];
        #pragma unroll
        for (int j = 0; j < 4; j++) xa[j] = *(const f4v*)(xp + j * 4);
        float s = 0.f, q = 0.f;
        #pragma unroll
        for (int j = 0; j < 4; j++)
            #pragma unroll
            for (int e = 0; e < 4; e++) { float v = xa[j][e]; s += v; q += v * v; }
        s += __shfl_xor(s, 1, 64); q += __shfl_xor(q, 1, 64);
        s += __shfl_xor(s, 2, 64); q += __shfl_xor(q, 2, 64);
        s += __shfl_xor(s, 4, 64); q += __shfl_xor(q, 4, 64);
        float mu = s * (1.f / 128.f);
        float rs = rsqrtf(q * (1.f / 128.f) - mu * mu + 1e-5f);
        #pragma unroll
        for (int half = 0; half < 2; half++) {
            int c = sub * 16 + half * 8;
            f4v gg0 = *(const f4v*)(g2 + c), gg1 = *(const f4v*)(g2 + c + 4);
            f4v bb0 = *(const f4v*)(b2 + c), bb1 = *(const f4v*)(b2 + c + 4);
            b8v o;
            #pragma unroll
            for (int e = 0; e < 4; e++) {
                o[e]     = (__bf16)((xa[half * 2][e]     - mu) * rs * gg0[e] + bb0[e]);
                o[4 + e] = (__bf16)((xa[half * 2 + 1][e] - mu) * rs * gg1[e] + bb1[e]);
            }
            *(b8v*)(x2 + (w * 8 + r) * 136 + c) = o;
        }
    }
    __syncthreads();

    // ---- A-fragments for ALL 32 rows into registers (8 b8v) ----
    b8v af[2][4];
    #pragma unroll
    for (int mt = 0; mt < 2; mt++)
        #pragma unroll
        for (int i = 0; i < 4; i++)
            af[mt][i] = *(const b8v*)&x2[(mt * 16 + r16) * 136 + quad * 8 + i * 32];
    __syncthreads();  // x2 region free; h1 writes may begin

    // ---- fc1 + exact GELU: wave w owns nt = w*8..w*8+7 (hidden cols) ----
    #pragma unroll 2
    for (int k8 = 0; k8 < 8; k8++) {
        const int nt = w * 8 + k8;
        const __bf16* bp = wfc1 + (nt * 16 + r16) * 128 + quad * 8;
        b8v Bf0 = *(const b8v*)(bp),      Bf1 = *(const b8v*)(bp + 32);
        b8v Bf2 = *(const b8v*)(bp + 64), Bf3 = *(const b8v*)(bp + 96);
        f4v acc0 = {0.f, 0.f, 0.f, 0.f}, acc1 = {0.f, 0.f, 0.f, 0.f};
        acc0 = mfma16(af[0][0], Bf0, acc0); acc1 = mfma16(af[1][0], Bf0, acc1);
        acc0 = mfma16(af[0][1], Bf1, acc0); acc1 = mfma16(af[1][1], Bf1, acc1);
        acc0 = mfma16(af[0][2], Bf2, acc0); acc1 = mfma16(af[1][2], Bf2, acc1);
        acc0 = mfma16(af[0][3], Bf3, acc0); acc1 = mfma16(af[1][3], Bf3, acc1);
        float bias = fc1_b[nt * 16 + r16];
        #pragma unroll
        for (int mt = 0; mt < 2; mt++) {
            #pragma unroll
            for (int rr = 0; rr < 4; rr++) {
                float v = (mt ? acc1[rr] : acc0[rr]) + bias;
                v = 0.5f * v * (1.f + erff(v * 0.70710678118654752f));
                h1[(mt * 16 + quad * 4 + rr) * 520 + nt * 16 + r16] = (__bf16)v;
            }
        }
    }
    __syncthreads();

    // ---- fc2: wave w owns out-cols (w*2..w*2+1)*16; A from shared h1 ----
    f4v acc[2][2];  // [j: out-tile][mt: row-tile]
    acc[0][0] = (f4v){0.f,0.f,0.f,0.f}; acc[0][1] = (f4v){0.f,0.f,0.f,0.f};
    acc[1][0] = (f4v){0.f,0.f,0.f,0.f}; acc[1][1] = (f4v){0.f,0.f,0.f,0.f};
    {
        const __bf16* bp0 = wfc2 + ((w * 2) * 16 + r16) * 512 + quad * 8;
        const __bf16* bp1 = bp0 + 16 * 512;
        #pragma unroll 4
        for (int ks = 0; ks < 16; ks++) {
            b8v a0 = *(const b8v*)&h1[r16 * 520 + ks * 32 + quad * 8];
            b8v a1 = *(const b8v*)&h1[(16 + r16) * 520 + ks * 32 + quad * 8];
            b8v B0 = *(const b8v*)(bp0 + ks * 32);
            b8v B1 = *(const b8v*)(bp1 + ks * 32);
            acc[0][0] = mfma16(a0, B0, acc[0][0]);
            acc[0][1] = mfma16(a1, B0, acc[0][1]);
            acc[1][0] = mfma16(a0, B1, acc[1][0]);
            acc[1][1] = mfma16(a1, B1, acc[1][1]);
        }
    }
    __syncthreads();  // all h1 reads complete before o_s overwrites the union

    // ---- fc2 D-frags + bias -> o_s ----
    #pragma unroll
    for (int j = 0; j < 2; j++) {
        int colb = (w * 2 + j) * 16 + r16;
        float fb = fc2_b[colb];
        #pragma unroll
        for (int mt = 0; mt < 2; mt++)
            #pragma unroll
            for (int rr = 0; rr < 4; rr++)
                o_s[(mt * 16 + quad * 4 + rr) * 130 + colb] = acc[j][mt][rr] + fb;
    }
    __syncthreads();

    // ---- vectorized residual RMW: thread -> 16 contiguous floats of out ----
    {
        const int row = tid >> 3, colb = (tid & 7) * 16;
        float* op = out + (rowbase + row) * Cc + colb;
        const float* ls = o_s + row * 130 + colb;
        #pragma unroll
        for (int j = 0; j < 4; j++) {
            f4v v = *(const f4v*)(op + j * 4);
            v += *(const f4v*)(ls + j * 4);
            *(f4v*)(op + j * 4) = v;
        }
    }
}

extern "C" void kernel_launch(void* const* d_in, const int* in_sizes, int n_in,
                              void* d_out, int out_size, void* d_ws, size_t ws_size,
                              hipStream_t stream) {
    // 0 x, 1 ln1_g, 2 ln1_b, 3 qkv_w, 4 qkv_b, 5 rpb_table, 6 proj_w, 7 proj_b,
    // 8 ln2_g, 9 ln2_b, 10 fc1_w, 11 fc1_b, 12 fc2_w, 13 fc2_b
    __bf16* wsb = (__bf16*)d_ws;
    float*  bmp = (float*)((char*)d_ws + 393216);
    prep_kernel<<<1024, 256, 0, stream>>>(
        (const float*)d_in[3], (const float*)d_in[6],
        (const float*)d_in[10], (const float*)d_in[12],
        (const float*)d_in[5], wsb, bmp);
    swin_kernel<<<B_ * 64, 256, 0, stream>>>(
        (const float*)d_in[0],
        (const float*)d_in[1], (const float*)d_in[2],
        (const float*)d_in[4], (const float*)d_in[7],
        wsb, wsb + 49152,
        bmp, (float*)d_out);
    mlp_kernel<<<B_ * 98, 256, 0, stream>>>(
        (float*)d_out,
        (const float*)d_in[8], (const float*)d_in[9],
        wsb + 65536, wsb + 131072,
        (const float*)d_in[11], (const float*)d_in[13]);
}

// Round 4
// 498.796 us; speedup vs baseline: 1.3604x; 1.3604x over previous
//
#include <hip/hip_runtime.h>
#include <math.h>

#define B_  64
#define Cc  128
#define L_  3136

typedef __bf16 b8v __attribute__((ext_vector_type(8)));
typedef __bf16 b4v __attribute__((ext_vector_type(4)));
typedef float  f4v __attribute__((ext_vector_type(4)));

__device__ __forceinline__ f4v mfma16(b8v a, b8v b, f4v c) {
    return __builtin_amdgcn_mfma_f32_16x16x32_bf16(a, b, c, 0, 0, 0);
}
__device__ __forceinline__ int region(int h, int w) {
    int a = (h < 49) ? 0 : ((h < 53) ? 1 : 2);
    int b = (w < 49) ? 0 : ((w < 53) ? 1 : 2);
    return a * 3 + b;
}

// ws layout: bf16 weights [0,196608) elems; biasmask f32[4][4][64][64] at byte 393216
__global__ __launch_bounds__(256) void prep_kernel(
    const float* __restrict__ qkv_w, const float* __restrict__ proj_w,
    const float* __restrict__ fc1_w, const float* __restrict__ fc2_w,
    const float* __restrict__ rpb,
    __bf16* __restrict__ wsb, float* __restrict__ bm)
{
    int i = blockIdx.x * 256 + threadIdx.x;
    if      (i <  49152) wsb[i] = (__bf16)qkv_w[i];
    else if (i <  65536) wsb[i] = (__bf16)proj_w[i - 49152];
    else if (i < 131072) wsb[i] = (__bf16)fc1_w[i - 65536];
    else if (i < 196608) wsb[i] = (__bf16)fc2_w[i - 131072];
    else {
        int idx = i - 196608;  // ((wt*4+h)*64+ii)*64+jj
        int jj = idx & 63, ii = (idx >> 6) & 63, h = (idx >> 12) & 3, wt = idx >> 14;
        float v;
        if (jj >= 49)      v = -1e30f;
        else if (ii >= 49) v = 0.f;
        else {
            int ih = ii / 7, iw = ii - ih * 7, jh = jj / 7, jw = jj - jh * 7;
            v = rpb[((ih - jh + 6) * 13 + (iw - jw + 6)) * 4 + h];
            int WH = (wt & 2) ? 49 : 0, WW = (wt & 1) ? 49 : 0;
            if (region(WH + ih, WW + iw) != region(WH + jh, WW + jw)) v -= 100.f;
        }
        bm[idx] = v;
    }
}

// ---- kernel A v4: LN1 + SW-MSA + proj + residual ----
// QKV and proj are N-sliced across waves: every weight byte loaded ONCE per
// block (was once per wave); 4 MFMAs per B-load. LDS 70656 -> 2 blocks/CU.
__global__ __launch_bounds__(256, 2) void swin_kernel(
    const float* __restrict__ x,
    const float* __restrict__ g1, const float* __restrict__ b1,
    const float* __restrict__ qkv_b, const float* __restrict__ proj_b,
    const __bf16* __restrict__ wqkv, const __bf16* __restrict__ wproj,
    const float* __restrict__ bm,
    float* __restrict__ out)
{
    __shared__ __bf16 a_s[64 * 136];   // LN1 out -> P bounce -> O staging
    __shared__ __bf16 Q_s[64 * 136];   // Q rows (all heads)
    __shared__ __bf16 K_s[64 * 136];   // K rows (all heads)
    __shared__ __bf16 VT_s[128 * 72];  // V^T [d][token]

    const int tid = threadIdx.x, w = tid >> 6, lane = tid & 63;
    const int quad = lane >> 4, r16 = lane & 15;
    const int blk = blockIdx.x, b = blk >> 6, wi = blk & 63;
    const int wh = wi >> 3, ww = wi & 7;
    const int wt = ((wh == 7) ? 2 : 0) | ((ww == 7) ? 1 : 0);
    const float scale = 0.17677669529663687f;  // 1/sqrt(32)

    // ---- LN1: wave w -> rows w*16..+15; each 16-lane group handles one row ----
    {
        f4v gg0 = *(const f4v*)(g1 + r16 * 8), gg1 = *(const f4v*)(g1 + r16 * 8 + 4);
        f4v bb0 = *(const f4v*)(b1 + r16 * 8), bb1 = *(const f4v*)(b1 + r16 * 8 + 4);
        #pragma unroll
        for (int it = 0; it < 4; it++) {
            int local = it * 4 + quad;
            int t = w * 16 + local;
            b8v o;
            #pragma unroll
            for (int e = 0; e < 8; e++) o[e] = (__bf16)0.f;
            if (t < 49) {   // group-uniform branch
                int th = t / 7, tw = t - th * 7;
                int sh = wh * 7 + th + 3; if (sh >= 56) sh -= 56;
                int sw = ww * 7 + tw + 3; if (sw >= 56) sw -= 56;
                const float* xp = x + (b * L_ + sh * 56 + sw) * Cc + r16 * 8;
                f4v x0 = *(const f4v*)(xp), x1 = *(const f4v*)(xp + 4);
                float s = 0.f, q = 0.f;
                #pragma unroll
                for (int e = 0; e < 4; e++) {
                    s += x0[e] + x1[e];
                    q += x0[e] * x0[e] + x1[e] * x1[e];
                }
                s += __shfl_xor(s, 1, 64); q += __shfl_xor(q, 1, 64);
                s += __shfl_xor(s, 2, 64); q += __shfl_xor(q, 2, 64);
                s += __shfl_xor(s, 4, 64); q += __shfl_xor(q, 4, 64);
                s += __shfl_xor(s, 8, 64); q += __shfl_xor(q, 8, 64);
                float mu = s * (1.f / 128.f);
                float rs = rsqrtf(q * (1.f / 128.f) - mu * mu + 1e-5f);
                #pragma unroll
                for (int e = 0; e < 4; e++) {
                    o[e]     = (__bf16)((x0[e] - mu) * rs * gg0[e] + bb0[e]);
                    o[4 + e] = (__bf16)((x1[e] - mu) * rs * gg1[e] + bb1[e]);
                }
            }
            *(b8v*)(a_s + local * 136 + w * 16 * 136 + r16 * 8) = o;
        }
    }
    __syncthreads();

    // ---- QKV, N-sliced: wave w -> qkv cols w*96..w*96+95, ALL 64 rows ----
    {
        b8v A[4][4];
        #pragma unroll
        for (int mt = 0; mt < 4; mt++)
            #pragma unroll
            for (int i = 0; i < 4; i++)
                A[mt][i] = *(const b8v*)(a_s + (mt * 16 + r16) * 136 + i * 32 + quad * 8);

        #pragma unroll
        for (int nt6 = 0; nt6 < 6; nt6++) {
            const int col = w * 96 + nt6 * 16;     // wave-uniform
            const __bf16* bp = wqkv + (col + r16) * 128 + quad * 8;
            b8v B0 = *(const b8v*)(bp),      B1 = *(const b8v*)(bp + 32);
            b8v B2 = *(const b8v*)(bp + 64), B3 = *(const b8v*)(bp + 96);
            float bias = qkv_b[col + r16];
            #pragma unroll
            for (int mt = 0; mt < 4; mt++) {
                f4v acc = {0.f, 0.f, 0.f, 0.f};
                acc = mfma16(A[mt][0], B0, acc);
                acc = mfma16(A[mt][1], B1, acc);
                acc = mfma16(A[mt][2], B2, acc);
                acc = mfma16(A[mt][3], B3, acc);
                if (col < 128) {          // Q
                    #pragma unroll
                    for (int r = 0; r < 4; r++)
                        Q_s[(mt * 16 + quad * 4 + r) * 136 + col + r16] =
                            (__bf16)((acc[r] + bias) * scale);
                } else if (col < 256) {   // K
                    #pragma unroll
                    for (int r = 0; r < 4; r++)
                        K_s[(mt * 16 + quad * 4 + r) * 136 + col - 128 + r16] =
                            (__bf16)(acc[r] + bias);
                } else {                  // V -> VT
                    b4v pk;
                    #pragma unroll
                    for (int r = 0; r < 4; r++) pk[r] = (__bf16)(acc[r] + bias);
                    *(b4v*)(VT_s + (col - 256 + r16) * 72 + mt * 16 + quad * 4) = pk;
                }
            }
        }
    }
    __syncthreads();

    // ---- all 4 heads: S -> softmax -> PV (P bounce wave-local via a_s strip) ----
    f4v o_acc[4][2];
    #pragma unroll
    for (int h = 0; h < 4; h++)
        #pragma unroll
        for (int n = 0; n < 2; n++)
            o_acc[h][n] = (f4v){0.f, 0.f, 0.f, 0.f};

    const float* bmw = bm + wt * 4 * 4096;
    __bf16* scr = a_s + w * 16 * 136;   // wave-local strip (LN1 data dead)

    #pragma unroll
    for (int h = 0; h < 4; h++) {
        b8v qf = *(const b8v*)(Q_s + (w * 16 + r16) * 136 + h * 32 + quad * 8);
        f4v s[4];
        #pragma unroll
        for (int nt = 0; nt < 4; nt++) {
            b8v kf = *(const b8v*)(K_s + (nt * 16 + r16) * 136 + h * 32 + quad * 8);
            f4v z = {0.f, 0.f, 0.f, 0.f};
            s[nt] = mfma16(qf, kf, z);
        }
        const float* bmp = bmw + h * 4096 + (w * 16 + quad * 4) * 64 + r16;
        #pragma unroll
        for (int nt = 0; nt < 4; nt++)
            #pragma unroll
            for (int r = 0; r < 4; r++)
                s[nt][r] += bmp[r * 64 + nt * 16];
        // softmax
        {
            float mx[4], sm[4];
            #pragma unroll
            for (int r = 0; r < 4; r++)
                mx[r] = fmaxf(fmaxf(s[0][r], s[1][r]), fmaxf(s[2][r], s[3][r]));
            #pragma unroll
            for (int mk = 1; mk < 16; mk <<= 1)
                #pragma unroll
                for (int r = 0; r < 4; r++)
                    mx[r] = fmaxf(mx[r], __shfl_xor(mx[r], mk, 64));
            #pragma unroll
            for (int r = 0; r < 4; r++) {
                s[0][r] = expf(s[0][r] - mx[r]);
                s[1][r] = expf(s[1][r] - mx[r]);
                s[2][r] = expf(s[2][r] - mx[r]);
                s[3][r] = expf(s[3][r] - mx[r]);
                sm[r] = s[0][r] + s[1][r] + s[2][r] + s[3][r];
            }
            #pragma unroll
            for (int mk = 1; mk < 16; mk <<= 1)
                #pragma unroll
                for (int r = 0; r < 4; r++)
                    sm[r] += __shfl_xor(sm[r], mk, 64);
            #pragma unroll
            for (int r = 0; r < 4; r++) {
                float inv = 1.f / sm[r];
                s[0][r] *= inv; s[1][r] *= inv; s[2][r] *= inv; s[3][r] *= inv;
            }
        }
        // P bounce (D->A) through wave-local strip
        #pragma unroll
        for (int nt = 0; nt < 4; nt++)
            #pragma unroll
            for (int r = 0; r < 4; r++)
                scr[(quad * 4 + r) * 136 + nt * 16 + r16] = (__bf16)s[nt][r];
        #pragma unroll
        for (int ks = 0; ks < 2; ks++) {
            b8v pf = *(const b8v*)(scr + r16 * 136 + ks * 32 + quad * 8);
            #pragma unroll
            for (int nt = 0; nt < 2; nt++) {
                b8v vf = *(const b8v*)(VT_s + (h * 32 + nt * 16 + r16) * 72 + ks * 32 + quad * 8);
                o_acc[h][nt] = mfma16(pf, vf, o_acc[h][nt]);
            }
        }
    }

    // ---- O -> a_s strip (shared), then N-sliced proj + residual ----
    #pragma unroll
    for (int h = 0; h < 4; h++)
        #pragma unroll
        for (int nt = 0; nt < 2; nt++)
            #pragma unroll
            for (int r = 0; r < 4; r++)
                scr[(quad * 4 + r) * 136 + h * 32 + nt * 16 + r16] = (__bf16)o_acc[h][nt][r];
    __syncthreads();

    {
        b8v O[4][4];
        #pragma unroll
        for (int mt = 0; mt < 4; mt++)
            #pragma unroll
            for (int i = 0; i < 4; i++)
                O[mt][i] = *(const b8v*)(a_s + (mt * 16 + r16) * 136 + i * 32 + quad * 8);

        #pragma unroll
        for (int nt = 0; nt < 2; nt++) {
            const int col = w * 32 + nt * 16;   // wave-uniform
            const __bf16* bp = wproj + (col + r16) * 128 + quad * 8;
            b8v B0 = *(const b8v*)(bp),      B1 = *(const b8v*)(bp + 32);
            b8v B2 = *(const b8v*)(bp + 64), B3 = *(const b8v*)(bp + 96);
            float pb = proj_b[col + r16];
            #pragma unroll
            for (int mt = 0; mt < 4; mt++) {
                f4v acc = {0.f, 0.f, 0.f, 0.f};
                acc = mfma16(O[mt][0], B0, acc);
                acc = mfma16(O[mt][1], B1, acc);
                acc = mfma16(O[mt][2], B2, acc);
                acc = mfma16(O[mt][3], B3, acc);
                #pragma unroll
                for (int r = 0; r < 4; r++) {
                    int t = mt * 16 + quad * 4 + r;
                    if (t < 49) {
                        int th = t / 7, tw = t - th * 7;
                        int sh = wh * 7 + th + 3; if (sh >= 56) sh -= 56;
                        int sw = ww * 7 + tw + 3; if (sw >= 56) sw -= 56;
                        int off = (b * L_ + sh * 56 + sw) * Cc + col + r16;
                        out[off] = x[off] + acc[r] + pb;
                    }
                }
            }
        }
    }
}

// ---- kernel B v3: LN2 + fc1 + GELU + fc2 + residual ----
// Tile = 128 tokens, 4 waves; hidden in 4 chunks of 128 with fc2 accumulators
// resident in registers. Weight bytes per token: 8.2 KB -> 2 KB.
// LDS 69632 -> 2 blocks/CU.
__global__ __launch_bounds__(256, 2) void mlp_kernel(
    float* __restrict__ out,
    const float* __restrict__ g2, const float* __restrict__ b2,
    const __bf16* __restrict__ wfc1, const __bf16* __restrict__ wfc2,
    const float* __restrict__ fc1_b, const float* __restrict__ fc2_b)
{
    __shared__ __align__(16) char u_s[69632];
    __bf16* x2 = (__bf16*)u_s;            // [128][136] LN2 out
    __bf16* h1 = (__bf16*)(u_s + 34816);  // [128][136] hidden chunk
    float*  o_s = (float*)u_s;            // [128][132] fc2 out (overlay at end)

    const int tid = threadIdx.x, w = tid >> 6, lane = tid & 63;
    const int quad = lane >> 4, r16 = lane & 15;
    const int rowbase = blockIdx.x * 128;

    // ---- LN2: 2 passes, 4 threads per row (32 ch each) ----
    #pragma unroll
    for (int p = 0; p < 2; p++) {
        const int r = p * 64 + (tid >> 2), sub = tid & 3;
        const float* xp = out + (rowbase + r) * Cc + sub * 32;
        f4v xa[8];
        #pragma unroll
        for (int j = 0; j < 8; j++) xa[j] = *(const f4v*)(xp + j * 4);
        float s = 0.f, q = 0.f;
        #pragma unroll
        for (int j = 0; j < 8; j++)
            #pragma unroll
            for (int e = 0; e < 4; e++) { float v = xa[j][e]; s += v; q += v * v; }
        s += __shfl_xor(s, 1, 64); q += __shfl_xor(q, 1, 64);
        s += __shfl_xor(s, 2, 64); q += __shfl_xor(q, 2, 64);
        float mu = s * (1.f / 128.f);
        float rs = rsqrtf(q * (1.f / 128.f) - mu * mu + 1e-5f);
        #pragma unroll
        for (int j = 0; j < 8; j += 2) {
            int c = sub * 32 + j * 4;
            f4v gg0 = *(const f4v*)(g2 + c), gg1 = *(const f4v*)(g2 + c + 4);
            f4v bb0 = *(const f4v*)(b2 + c), bb1 = *(const f4v*)(b2 + c + 4);
            b8v o;
            #pragma unroll
            for (int e = 0; e < 4; e++) {
                o[e]     = (__bf16)((xa[j][e]     - mu) * rs * gg0[e] + bb0[e]);
                o[4 + e] = (__bf16)((xa[j + 1][e] - mu) * rs * gg1[e] + bb1[e]);
            }
            *(b8v*)(x2 + r * 136 + c) = o;
        }
    }
    __syncthreads();

    // fc2 accumulators: wave w -> out cols w*32..+31 (2 N-tiles), 8 M-tiles
    f4v acc[8][2];
    #pragma unroll
    for (int mt = 0; mt < 8; mt++)
        #pragma unroll
        for (int nt = 0; nt < 2; nt++)
            acc[mt][nt] = (f4v){0.f, 0.f, 0.f, 0.f};

    for (int hc = 0; hc < 4; hc++) {
        // ---- fc1 + GELU: wave w -> hidden cols hc*128 + w*32..+31 ----
        {
            b8v Bf[2][4]; float bias[2];
            #pragma unroll
            for (int nt = 0; nt < 2; nt++) {
                const int col = hc * 128 + w * 32 + nt * 16;
                const __bf16* bp = wfc1 + (col + r16) * 128 + quad * 8;
                Bf[nt][0] = *(const b8v*)(bp);      Bf[nt][1] = *(const b8v*)(bp + 32);
                Bf[nt][2] = *(const b8v*)(bp + 64); Bf[nt][3] = *(const b8v*)(bp + 96);
                bias[nt] = fc1_b[col + r16];
            }
            #pragma unroll 2
            for (int mt = 0; mt < 8; mt++) {
                const __bf16* ap = x2 + (mt * 16 + r16) * 136 + quad * 8;
                b8v A0 = *(const b8v*)(ap),      A1 = *(const b8v*)(ap + 32);
                b8v A2 = *(const b8v*)(ap + 64), A3 = *(const b8v*)(ap + 96);
                f4v a0 = {0.f, 0.f, 0.f, 0.f}, a1 = {0.f, 0.f, 0.f, 0.f};
                a0 = mfma16(A0, Bf[0][0], a0); a1 = mfma16(A0, Bf[1][0], a1);
                a0 = mfma16(A1, Bf[0][1], a0); a1 = mfma16(A1, Bf[1][1], a1);
                a0 = mfma16(A2, Bf[0][2], a0); a1 = mfma16(A2, Bf[1][2], a1);
                a0 = mfma16(A3, Bf[0][3], a0); a1 = mfma16(A3, Bf[1][3], a1);
                #pragma unroll
                for (int r = 0; r < 4; r++) {
                    float v0 = a0[r] + bias[0];
                    float v1 = a1[r] + bias[1];
                    v0 = 0.5f * v0 * (1.f + erff(v0 * 0.70710678118654752f));
                    v1 = 0.5f * v1 * (1.f + erff(v1 * 0.70710678118654752f));
                    h1[(mt * 16 + quad * 4 + r) * 136 + w * 32 + r16]      = (__bf16)v0;
                    h1[(mt * 16 + quad * 4 + r) * 136 + w * 32 + 16 + r16] = (__bf16)v1;
                }
            }
        }
        __syncthreads();
        // ---- fc2 partial accumulation over this hidden chunk ----
        #pragma unroll
        for (int Ks = 0; Ks < 4; Ks++) {
            b8v Af[8];
            #pragma unroll
            for (int mt = 0; mt < 8; mt++)
                Af[mt] = *(const b8v*)(h1 + (mt * 16 + r16) * 136 + Ks * 32 + quad * 8);
            #pragma unroll
            for (int nt = 0; nt < 2; nt++) {
                const __bf16* bp = wfc2 + (w * 32 + nt * 16 + r16) * 512
                                 + hc * 128 + Ks * 32 + quad * 8;
                b8v Bf = *(const b8v*)(bp);
                #pragma unroll
                for (int mt = 0; mt < 8; mt++)
                    acc[mt][nt] = mfma16(Af[mt], Bf, acc[mt][nt]);
            }
        }
        __syncthreads();
    }

    // ---- bias -> o_s (overlay; x2/h1 dead) ----
    #pragma unroll
    for (int nt = 0; nt < 2; nt++) {
        const int col = w * 32 + nt * 16 + r16;
        const float fb = fc2_b[col];
        #pragma unroll
        for (int mt = 0; mt < 8; mt++)
            #pragma unroll
            for (int r = 0; r < 4; r++)
                o_s[(mt * 16 + quad * 4 + r) * 132 + col] = acc[mt][nt][r] + fb;
    }
    __syncthreads();

    // ---- vectorized residual RMW: thread -> 16 contiguous floats, 4 passes ----
    #pragma unroll
    for (int p = 0; p < 4; p++) {
        const int row = p * 32 + (tid >> 3), colb = (tid & 7) * 16;
        float* op = out + (rowbase + row) * Cc + colb;
        const float* ls = o_s + row * 132 + colb;
        #pragma unroll
        for (int j = 0; j < 4; j++) {
            f4v v = *(const f4v*)(op + j * 4);
            v += *(const f4v*)(ls + j * 4);
            *(f4v*)(op + j * 4) = v;
        }
    }
}

extern "C" void kernel_launch(void* const* d_in, const int* in_sizes, int n_in,
                              void* d_out, int out_size, void* d_ws, size_t ws_size,
                              hipStream_t stream) {
    // 0 x, 1 ln1_g, 2 ln1_b, 3 qkv_w, 4 qkv_b, 5 rpb_table, 6 proj_w, 7 proj_b,
    // 8 ln2_g, 9 ln2_b, 10 fc1_w, 11 fc1_b, 12 fc2_w, 13 fc2_b
    __bf16* wsb = (__bf16*)d_ws;
    float*  bmp = (float*)((char*)d_ws + 393216);
    prep_kernel<<<1024, 256, 0, stream>>>(
        (const float*)d_in[3], (const float*)d_in[6],
        (const float*)d_in[10], (const float*)d_in[12],
        (const float*)d_in[5], wsb, bmp);
    swin_kernel<<<B_ * 64, 256, 0, stream>>>(
        (const float*)d_in[0],
        (const float*)d_in[1], (const float*)d_in[2],
        (const float*)d_in[4], (const float*)d_in[7],
        wsb, wsb + 49152,
        bmp, (float*)d_out);
    mlp_kernel<<<(B_ * L_) / 128, 256, 0, stream>>>(
        (float*)d_out,
        (const float*)d_in[8], (const float*)d_in[9],
        wsb + 65536, wsb + 131072,
        (const float*)d_in[11], (const float*)d_in[13]);
}

// Round 7
// 466.951 us; speedup vs baseline: 1.4532x; 1.0682x over previous
//
// v5 resubmission #3 — audited for fault/hang vectors; see round-6 notes.
#include <hip/hip_runtime.h>
#include <math.h>

#define B_  64
#define Cc  128
#define L_  3136

typedef __bf16 b8v __attribute__((ext_vector_type(8)));
typedef __bf16 b4v __attribute__((ext_vector_type(4)));
typedef float  f4v __attribute__((ext_vector_type(4)));

__device__ __forceinline__ f4v mfma16(b8v a, b8v b, f4v c) {
    return __builtin_amdgcn_mfma_f32_16x16x32_bf16(a, b, c, 0, 0, 0);
}
__device__ __forceinline__ int region(int h, int w) {
    int a = (h < 49) ? 0 : ((h < 53) ? 1 : 2);
    int b = (w < 49) ? 0 : ((w < 53) ? 1 : 2);
    return a * 3 + b;
}

// ws layout: bf16 weights [0,196608) elems; biasmask f32[4][4][64][64] at byte 393216
__global__ __launch_bounds__(256) void prep_kernel(
    const float* __restrict__ qkv_w, const float* __restrict__ proj_w,
    const float* __restrict__ fc1_w, const float* __restrict__ fc2_w,
    const float* __restrict__ rpb,
    __bf16* __restrict__ wsb, float* __restrict__ bm)
{
    int i = blockIdx.x * 256 + threadIdx.x;
    if      (i <  49152) wsb[i] = (__bf16)qkv_w[i];
    else if (i <  65536) wsb[i] = (__bf16)proj_w[i - 49152];
    else if (i < 131072) wsb[i] = (__bf16)fc1_w[i - 65536];
    else if (i < 196608) wsb[i] = (__bf16)fc2_w[i - 131072];
    else {
        int idx = i - 196608;  // ((wt*4+h)*64+ii)*64+jj
        int jj = idx & 63, ii = (idx >> 6) & 63, h = (idx >> 12) & 3, wt = idx >> 14;
        float v;
        if (jj >= 49)      v = -1e30f;
        else if (ii >= 49) v = 0.f;
        else {
            int ih = ii / 7, iw = ii - ih * 7, jh = jj / 7, jw = jj - jh * 7;
            v = rpb[((ih - jh + 6) * 13 + (iw - jw + 6)) * 4 + h];
            int WH = (wt & 2) ? 49 : 0, WW = (wt & 1) ? 49 : 0;
            if (region(WH + ih, WW + iw) != region(WH + jh, WW + jw)) v -= 100.f;
        }
        bm[idx] = v;
    }
}

// ---- kernel A v5: LN1 + SW-MSA + proj + residual ----
// Q overlays a_s (LN1 buffer dead after A-frag caching) -> LDS 53248 ->
// 3 blocks/CU. Swapped MFMA operand order gives column-contiguous D-frags:
// all LDS stores b4v, epilogue f4v. Softmax: no max pass (S bounded, pads
// are -1e30 -> exp == 0), 2 shfl_xor per head.
__global__ __launch_bounds__(256, 3) void swin_kernel(
    const float* __restrict__ x,
    const float* __restrict__ g1, const float* __restrict__ b1,
    const float* __restrict__ qkv_b, const float* __restrict__ proj_b,
    const __bf16* __restrict__ wqkv, const __bf16* __restrict__ wproj,
    const float* __restrict__ bm,
    float* __restrict__ out)
{
    __shared__ __bf16 a_s[64 * 136];   // LN1 -> Q overlay -> P scratch -> O
    __shared__ __bf16 K_s[64 * 136];   // K rows (all heads)
    __shared__ __bf16 VT_s[128 * 72];  // V^T [d][token]

    const int tid = threadIdx.x, w = tid >> 6, lane = tid & 63;
    const int quad = lane >> 4, r16 = lane & 15;
    const int blk = blockIdx.x, b = blk >> 6, wi = blk & 63;
    const int wh = wi >> 3, ww = wi & 7;
    const int wt = ((wh == 7) ? 2 : 0) | ((ww == 7) ? 1 : 0);
    const float scale = 0.17677669529663687f;  // 1/sqrt(32)

    // ---- LN1: wave w -> rows w*16..+15; 16-lane group per row ----
    {
        f4v gg0 = *(const f4v*)(g1 + r16 * 8), gg1 = *(const f4v*)(g1 + r16 * 8 + 4);
        f4v bb0 = *(const f4v*)(b1 + r16 * 8), bb1 = *(const f4v*)(b1 + r16 * 8 + 4);
        #pragma unroll
        for (int it = 0; it < 4; it++) {
            int local = it * 4 + quad;
            int t = w * 16 + local;
            b8v o;
            #pragma unroll
            for (int e = 0; e < 8; e++) o[e] = (__bf16)0.f;
            if (t < 49) {   // group-uniform branch
                int th = t / 7, tw = t - th * 7;
                int sh = wh * 7 + th + 3; if (sh >= 56) sh -= 56;
                int sw = ww * 7 + tw + 3; if (sw >= 56) sw -= 56;
                const float* xp = x + (b * L_ + sh * 56 + sw) * Cc + r16 * 8;
                f4v x0 = *(const f4v*)(xp), x1 = *(const f4v*)(xp + 4);
                float s = 0.f, q = 0.f;
                #pragma unroll
                for (int e = 0; e < 4; e++) {
                    s += x0[e] + x1[e];
                    q += x0[e] * x0[e] + x1[e] * x1[e];
                }
                s += __shfl_xor(s, 1, 64); q += __shfl_xor(q, 1, 64);
                s += __shfl_xor(s, 2, 64); q += __shfl_xor(q, 2, 64);
                s += __shfl_xor(s, 4, 64); q += __shfl_xor(q, 4, 64);
                s += __shfl_xor(s, 8, 64); q += __shfl_xor(q, 8, 64);
                float mu = s * (1.f / 128.f);
                float rs = rsqrtf(q * (1.f / 128.f) - mu * mu + 1e-5f);
                #pragma unroll
                for (int e = 0; e < 4; e++) {
                    o[e]     = (__bf16)((x0[e] - mu) * rs * gg0[e] + bb0[e]);
                    o[4 + e] = (__bf16)((x1[e] - mu) * rs * gg1[e] + bb1[e]);
                }
            }
            *(b8v*)(a_s + (w * 16 + local) * 136 + r16 * 8) = o;
        }
    }
    __syncthreads();

    // ---- cache A-fragments (all 64 rows) ----
    b8v A[4][4];
    #pragma unroll
    for (int mt = 0; mt < 4; mt++)
        #pragma unroll
        for (int i = 0; i < 4; i++)
            A[mt][i] = *(const b8v*)(a_s + (mt * 16 + r16) * 136 + i * 32 + quad * 8);
    __syncthreads();   // all waves done reading a_s; Q may overlay it

    // ---- QKV N-sliced: wave w -> cols w*96..+95; Q/K swapped, V unswapped ----
    #pragma unroll
    for (int nt6 = 0; nt6 < 6; nt6++) {
        const int col = w * 96 + nt6 * 16;    // wave-uniform
        const __bf16* bp = wqkv + (col + r16) * 128 + quad * 8;
        b8v B0 = *(const b8v*)(bp),      B1 = *(const b8v*)(bp + 32);
        b8v B2 = *(const b8v*)(bp + 64), B3 = *(const b8v*)(bp + 96);
        if (col < 256) {   // Q or K: D[qkcol][token], lane holds 4 contig cols
            f4v qb = *(const f4v*)(qkv_b + col + quad * 4);
            #pragma unroll
            for (int mt = 0; mt < 4; mt++) {
                f4v acc = {0.f, 0.f, 0.f, 0.f};
                acc = mfma16(B0, A[mt][0], acc);
                acc = mfma16(B1, A[mt][1], acc);
                acc = mfma16(B2, A[mt][2], acc);
                acc = mfma16(B3, A[mt][3], acc);
                b4v pk;
                if (col < 128) {
                    #pragma unroll
                    for (int r = 0; r < 4; r++) pk[r] = (__bf16)((acc[r] + qb[r]) * scale);
                    *(b4v*)(a_s + (mt * 16 + r16) * 136 + col + quad * 4) = pk;
                } else {
                    #pragma unroll
                    for (int r = 0; r < 4; r++) pk[r] = (__bf16)(acc[r] + qb[r]);
                    *(b4v*)(K_s + (mt * 16 + r16) * 136 + (col - 128) + quad * 4) = pk;
                }
            }
        } else {           // V: D[token][vcol]; 4 contig tokens -> VT rows
            float vb = qkv_b[col + r16];
            #pragma unroll
            for (int mt = 0; mt < 4; mt++) {
                f4v acc = {0.f, 0.f, 0.f, 0.f};
                acc = mfma16(A[mt][0], B0, acc);
                acc = mfma16(A[mt][1], B1, acc);
                acc = mfma16(A[mt][2], B2, acc);
                acc = mfma16(A[mt][3], B3, acc);
                b4v pk;
                #pragma unroll
                for (int r = 0; r < 4; r++) pk[r] = (__bf16)(acc[r] + vb);
                *(b4v*)(VT_s + (col - 256 + r16) * 72 + mt * 16 + quad * 4) = pk;
            }
        }
    }
    __syncthreads();

    // ---- preload own-strip Q for all heads (P scratch will overwrite it) ----
    b8v qf[4];
    #pragma unroll
    for (int h = 0; h < 4; h++)
        qf[h] = *(const b8v*)(a_s + (w * 16 + r16) * 136 + h * 32 + quad * 8);

    __bf16* scr = a_s + (w * 16) * 136;    // wave-local strip
    const float* bmq = bm + wt * 4 * 4096 + (w * 16 + r16) * 64;

    f4v o_acc[4][2];
    #pragma unroll
    for (int h = 0; h < 4; h++)
        #pragma unroll
        for (int n = 0; n < 2; n++)
            o_acc[h][n] = (f4v){0.f, 0.f, 0.f, 0.f};

    #pragma unroll
    for (int h = 0; h < 4; h++) {
        // S swapped: D[k][q]; lane r16 = own q-row, regs span 16 k
        f4v s[4];
        #pragma unroll
        for (int nt = 0; nt < 4; nt++) {
            b8v kf = *(const b8v*)(K_s + (nt * 16 + r16) * 136 + h * 32 + quad * 8);
            f4v z = {0.f, 0.f, 0.f, 0.f};
            s[nt] = mfma16(kf, qf[h], z);
        }
        // bias+mask (f4v) + exp (no max pass; pads are -1e30 -> exp==0)
        float sm = 0.f;
        #pragma unroll
        for (int nt = 0; nt < 4; nt++) {
            f4v mb = *(const f4v*)(bmq + h * 4096 + nt * 16 + quad * 4);
            #pragma unroll
            for (int r = 0; r < 4; r++) {
                s[nt][r] = __expf(s[nt][r] + mb[r]);
                sm += s[nt][r];
            }
        }
        sm += __shfl_xor(sm, 16, 64);
        sm += __shfl_xor(sm, 32, 64);
        float inv = 1.f / sm;
        // P -> wave-local scratch (b4v, row = own q-row r16)
        #pragma unroll
        for (int nt = 0; nt < 4; nt++) {
            b4v pk;
            #pragma unroll
            for (int r = 0; r < 4; r++) pk[r] = (__bf16)(s[nt][r] * inv);
            *(b4v*)(scr + r16 * 136 + nt * 16 + quad * 4) = pk;
        }
        // PV swapped: D[d][q] accumulates in regs
        #pragma unroll
        for (int ks = 0; ks < 2; ks++) {
            b8v pf = *(const b8v*)(scr + r16 * 136 + ks * 32 + quad * 8);
            #pragma unroll
            for (int nt = 0; nt < 2; nt++) {
                b8v vf = *(const b8v*)(VT_s + (h * 32 + nt * 16 + r16) * 72 + ks * 32 + quad * 8);
                o_acc[h][nt] = mfma16(vf, pf, o_acc[h][nt]);
            }
        }
    }

    // ---- O -> strip (b4v; lane r16 = own q-row, 4 contig d) ----
    #pragma unroll
    for (int h = 0; h < 4; h++)
        #pragma unroll
        for (int nt = 0; nt < 2; nt++) {
            b4v pk;
            #pragma unroll
            for (int r = 0; r < 4; r++) pk[r] = (__bf16)o_acc[h][nt][r];
            *(b4v*)(scr + r16 * 136 + h * 32 + nt * 16 + quad * 4) = pk;
        }
    __syncthreads();

    // ---- proj swapped + residual: f4v RMW, 4 contig out cols per lane ----
    {
        b8v O[4][4];
        #pragma unroll
        for (int mt = 0; mt < 4; mt++)
            #pragma unroll
            for (int i = 0; i < 4; i++)
                O[mt][i] = *(const b8v*)(a_s + (mt * 16 + r16) * 136 + i * 32 + quad * 8);

        #pragma unroll
        for (int nt = 0; nt < 2; nt++) {
            const int col = w * 32 + nt * 16;   // wave-uniform
            const __bf16* bp = wproj + (col + r16) * 128 + quad * 8;
            b8v B0 = *(const b8v*)(bp),      B1 = *(const b8v*)(bp + 32);
            b8v B2 = *(const b8v*)(bp + 64), B3 = *(const b8v*)(bp + 96);
            f4v pb = *(const f4v*)(proj_b + col + quad * 4);
            #pragma unroll
            for (int mt = 0; mt < 4; mt++) {
                f4v acc = {0.f, 0.f, 0.f, 0.f};
                acc = mfma16(B0, O[mt][0], acc);
                acc = mfma16(B1, O[mt][1], acc);
                acc = mfma16(B2, O[mt][2], acc);
                acc = mfma16(B3, O[mt][3], acc);
                int t = mt * 16 + r16;
                if (t < 49) {
                    int th = t / 7, tw = t - th * 7;
                    int sh = wh * 7 + th + 3; if (sh >= 56) sh -= 56;
                    int sw = ww * 7 + tw + 3; if (sw >= 56) sw -= 56;
                    int off = (b * L_ + sh * 56 + sw) * Cc + col + quad * 4;
                    f4v xr = *(const f4v*)(x + off);
                    f4v res;
                    #pragma unroll
                    for (int r = 0; r < 4; r++) res[r] = xr[r] + acc[r] + pb[r];
                    *(f4v*)(out + off) = res;
                }
            }
        }
    }
}

// ---- kernel B v4: LN2 + fc1 + GELU + fc2 + residual ----
// 64-token tile, LDS 34816 -> 4 blocks/CU. Swapped MFMA: h1 stores b4v,
// fc2 result stays in regs -> direct coalesced f4v residual RMW (no o_s).
__global__ __launch_bounds__(256, 4) void mlp_kernel(
    float* __restrict__ out,
    const float* __restrict__ g2, const float* __restrict__ b2,
    const __bf16* __restrict__ wfc1, const __bf16* __restrict__ wfc2,
    const float* __restrict__ fc1_b, const float* __restrict__ fc2_b)
{
    __shared__ __bf16 x2[64 * 136];   // LN2 out
    __shared__ __bf16 h1[64 * 136];   // hidden chunk (128 cols)

    const int tid = threadIdx.x, w = tid >> 6, lane = tid & 63;
    const int quad = lane >> 4, r16 = lane & 15;
    const int rowbase = blockIdx.x * 64;

    // ---- LN2: 4 threads per row (32 ch each) ----
    {
        const int r = tid >> 2, sub = tid & 3;
        const float* xp = out + (rowbase + r) * Cc + sub * 32;
        f4v xa[8];
        #pragma unroll
        for (int j = 0; j < 8; j++) xa[j] = *(const f4v*)(xp + j * 4);
        float s = 0.f, q = 0.f;
        #pragma unroll
        for (int j = 0; j < 8; j++)
            #pragma unroll
            for (int e = 0; e < 4; e++) { float v = xa[j][e]; s += v; q += v * v; }
        s += __shfl_xor(s, 1, 64); q += __shfl_xor(q, 1, 64);
        s += __shfl_xor(s, 2, 64); q += __shfl_xor(q, 2, 64);
        float mu = s * (1.f / 128.f);
        float rs = rsqrtf(q * (1.f / 128.f) - mu * mu + 1e-5f);
        #pragma unroll
        for (int j = 0; j < 8; j += 2) {
            int c = sub * 32 + j * 4;
            f4v gg0 = *(const f4v*)(g2 + c), gg1 = *(const f4v*)(g2 + c + 4);
            f4v bb0 = *(const f4v*)(b2 + c), bb1 = *(const f4v*)(b2 + c + 4);
            b8v o;
            #pragma unroll
            for (int e = 0; e < 4; e++) {
                o[e]     = (__bf16)((xa[j][e]     - mu) * rs * gg0[e] + bb0[e]);
                o[4 + e] = (__bf16)((xa[j + 1][e] - mu) * rs * gg1[e] + bb1[e]);
            }
            *(b8v*)(x2 + r * 136 + c) = o;
        }
    }
    __syncthreads();

    f4v acc[4][2];   // fc2 accumulators: D[ocol][token]
    #pragma unroll
    for (int mt = 0; mt < 4; mt++)
        #pragma unroll
        for (int nt = 0; nt < 2; nt++)
            acc[mt][nt] = (f4v){0.f, 0.f, 0.f, 0.f};

    for (int hc = 0; hc < 4; hc++) {
        // ---- fc1 swapped + GELU: wave w -> hidden cols hc*128 + w*32..+31 ----
        {
            b8v Bf[2][4]; f4v b14[2];
            #pragma unroll
            for (int nt = 0; nt < 2; nt++) {
                const int col = hc * 128 + w * 32 + nt * 16;
                const __bf16* bp = wfc1 + (col + r16) * 128 + quad * 8;
                Bf[nt][0] = *(const b8v*)(bp);      Bf[nt][1] = *(const b8v*)(bp + 32);
                Bf[nt][2] = *(const b8v*)(bp + 64); Bf[nt][3] = *(const b8v*)(bp + 96);
                b14[nt] = *(const f4v*)(fc1_b + col + quad * 4);
            }
            #pragma unroll
            for (int mt = 0; mt < 4; mt++) {
                const __bf16* ap = x2 + (mt * 16 + r16) * 136 + quad * 8;
                b8v A0 = *(const b8v*)(ap),      A1 = *(const b8v*)(ap + 32);
                b8v A2 = *(const b8v*)(ap + 64), A3 = *(const b8v*)(ap + 96);
                #pragma unroll
                for (int nt = 0; nt < 2; nt++) {
                    f4v a = {0.f, 0.f, 0.f, 0.f};
                    a = mfma16(Bf[nt][0], A0, a);
                    a = mfma16(Bf[nt][1], A1, a);
                    a = mfma16(Bf[nt][2], A2, a);
                    a = mfma16(Bf[nt][3], A3, a);
                    b4v pk;
                    #pragma unroll
                    for (int r = 0; r < 4; r++) {
                        float v = a[r] + b14[nt][r];
                        v = 0.5f * v * (1.f + erff(v * 0.70710678118654752f));
                        pk[r] = (__bf16)v;
                    }
                    *(b4v*)(h1 + (mt * 16 + r16) * 136 + w * 32 + nt * 16 + quad * 4) = pk;
                }
            }
        }
        __syncthreads();
        // ---- fc2 partial (swapped): wave w -> out cols w*32..+31 ----
        #pragma unroll
        for (int Ks = 0; Ks < 4; Ks++) {
            b8v Af[4];
            #pragma unroll
            for (int mt = 0; mt < 4; mt++)
                Af[mt] = *(const b8v*)(h1 + (mt * 16 + r16) * 136 + Ks * 32 + quad * 8);
            #pragma unroll
            for (int nt = 0; nt < 2; nt++) {
                const __bf16* bp = wfc2 + (w * 32 + nt * 16 + r16) * 512
                                 + hc * 128 + Ks * 32 + quad * 8;
                b8v Bf = *(const b8v*)(bp);
                #pragma unroll
                for (int mt = 0; mt < 4; mt++)
                    acc[mt][nt] = mfma16(Bf, Af[mt], acc[mt][nt]);
            }
        }
        if (hc < 3) __syncthreads();
    }

    // ---- epilogue: direct coalesced f4v residual RMW ----
    #pragma unroll
    for (int nt = 0; nt < 2; nt++) {
        const int col = w * 32 + nt * 16 + quad * 4;
        f4v fb = *(const f4v*)(fc2_b + col);
        #pragma unroll
        for (int mt = 0; mt < 4; mt++) {
            float* op = out + (rowbase + mt * 16 + r16) * Cc + col;
            f4v v = *(const f4v*)op;
            #pragma unroll
            for (int r = 0; r < 4; r++) v[r] += acc[mt][nt][r] + fb[r];
            *(f4v*)op = v;
        }
    }
}

extern "C" void kernel_launch(void* const* d_in, const int* in_sizes, int n_in,
                              void* d_out, int out_size, void* d_ws, size_t ws_size,
                              hipStream_t stream) {
    // 0 x, 1 ln1_g, 2 ln1_b, 3 qkv_w, 4 qkv_b, 5 rpb_table, 6 proj_w, 7 proj_b,
    // 8 ln2_g, 9 ln2_b, 10 fc1_w, 11 fc1_b, 12 fc2_w, 13 fc2_b
    __bf16* wsb = (__bf16*)d_ws;
    float*  bmp = (float*)((char*)d_ws + 393216);
    prep_kernel<<<1024, 256, 0, stream>>>(
        (const float*)d_in[3], (const float*)d_in[6],
        (const float*)d_in[10], (const float*)d_in[12],
        (const float*)d_in[5], wsb, bmp);
    swin_kernel<<<B_ * 64, 256, 0, stream>>>(
        (const float*)d_in[0],
        (const float*)d_in[1], (const float*)d_in[2],
        (const float*)d_in[4], (const float*)d_in[7],
        wsb, wsb + 49152,
        bmp, (float*)d_out);
    mlp_kernel<<<(B_ * L_) / 64, 256, 0, stream>>>(
        (float*)d_out,
        (const float*)d_in[8], (const float*)d_in[9],
        wsb + 65536, wsb + 131072,
        (const float*)d_in[11], (const float*)d_in[13]);
}